// Round 6
// baseline (681.019 us; speedup 1.0000x reference)
//
#include <hip/hip_runtime.h>
#include <hip/hip_bf16.h>
#include <math.h>

#define B_    2048
#define IND   20000
#define ENCN  512
#define BOTN  128
#define DECN  512
#define KP1   20480   // IND padded to 64*320
#define NP    20224   // IND padded to 79*256
#define SPLITK 16
#define KSTEP1 20     // 16*20*64 = 20480
#define SPLITK2 4
#define BNEPS 1e-5f

typedef __hip_bfloat16 bf16;
typedef __bf16 bf16x8 __attribute__((ext_vector_type(8)));
typedef float f32x4 __attribute__((ext_vector_type(4)));
typedef unsigned short u16;

__device__ __forceinline__ u16 f2bfu(float f) {
  __hip_bfloat16 h = __float2bfloat16(f);
  return *reinterpret_cast<u16*>(&h);
}

__device__ __forceinline__ void st_b64_bf16(void* p, f32x4 v) {
  union { u16 u[4]; uint2 d; } o;
  o.u[0] = f2bfu(v[0]); o.u[1] = f2bfu(v[1]);
  o.u[2] = f2bfu(v[2]); o.u[3] = f2bfu(v[3]);
  *(uint2*)p = o.d;
}

__device__ __forceinline__ void gload_lds16(const bf16* g, bf16* l) {
  __builtin_amdgcn_global_load_lds(
      (const __attribute__((address_space(1))) void*)g,
      (__attribute__((address_space(3))) void*)l, 16, 0, 0);
}

// ---------------- row sums ----------------
__global__ void rowsum_k(const float* __restrict__ x, float* __restrict__ row_sum) {
  const int row = blockIdx.x;
  const f32x4* xr = (const f32x4*)(x + (size_t)row * IND);
  float s = 0.f;
  for (int i = threadIdx.x; i < IND / 4; i += 256) {
    f32x4 v = xr[i];
    s += (v[0] + v[1]) + (v[2] + v[3]);
  }
#pragma unroll
  for (int o = 32; o > 0; o >>= 1) s += __shfl_down(s, o, 64);
  __shared__ float ws4[4];
  if ((threadIdx.x & 63) == 0) ws4[threadIdx.x >> 6] = s;
  __syncthreads();
  if (threadIdx.x == 0) row_sum[row] = (ws4[0] + ws4[1]) + (ws4[2] + ws4[3]);
}

// ---------------- median + per-row scale ----------------
__global__ void median_scale_k(const float* __restrict__ row_sum,
                               float* __restrict__ sArr, float* __restrict__ invs) {
  __shared__ float v[B_];
  const int tid = threadIdx.x;  // 1024 threads
  v[tid] = row_sum[tid];
  v[tid + 1024] = row_sum[tid + 1024];
  __syncthreads();
  for (int k = 2; k <= B_; k <<= 1) {
    for (int j = k >> 1; j > 0; j >>= 1) {
      for (int i = tid; i < B_; i += 1024) {
        int ixj = i ^ j;
        if (ixj > i) {
          bool up = ((i & k) == 0);
          float a = v[i], b = v[ixj];
          if ((a > b) == up) { v[i] = b; v[ixj] = a; }
        }
      }
      __syncthreads();
    }
  }
  float med = 0.5f * (v[B_ / 2 - 1] + v[B_ / 2]);
  for (int i = tid; i < B_; i += 1024) {
    float rs = row_sum[i];
    sArr[i] = rs / med;
    invs[i] = med / rs;
  }
}

// ---------------- pass2: L = bf16(log1p(x*invs)), partial col sums/sumsq ----------------
__global__ void pass2_k(const float* __restrict__ x, const float* __restrict__ invs,
                        bf16* __restrict__ L, float* __restrict__ part_s,
                        float* __restrict__ part_q) {
  const int c0 = (blockIdx.x * 256 + threadIdx.x) * 4;   // 0..20476
  const int rblk = blockIdx.y;
  const int r0 = rblk * 32;
  const bool valid = (c0 < IND);
  f32x4 sum = {0.f, 0.f, 0.f, 0.f}, sq = {0.f, 0.f, 0.f, 0.f};
  for (int r = r0; r < r0 + 32; ++r) {
    f32x4 lv = {0.f, 0.f, 0.f, 0.f};
    if (valid) {
      f32x4 v = *(const f32x4*)(x + (size_t)r * IND + c0);
      float iv = invs[r];
      lv[0] = log1pf(v[0] * iv); lv[1] = log1pf(v[1] * iv);
      lv[2] = log1pf(v[2] * iv); lv[3] = log1pf(v[3] * iv);
      sum += lv; sq += lv * lv;
    }
    ushort4 o;
    o.x = f2bfu(lv[0]); o.y = f2bfu(lv[1]); o.z = f2bfu(lv[2]); o.w = f2bfu(lv[3]);
    *(ushort4*)((u16*)L + (size_t)r * KP1 + c0) = o;
  }
  if (valid) {
    *(f32x4*)(part_s + (size_t)rblk * KP1 + c0) = sum;
    *(f32x4*)(part_q + (size_t)rblk * KP1 + c0) = sq;
  }
}

// ---------------- finalize BN0 from 64 partials ----------------
__global__ void finalize_bn_k(const float* __restrict__ part_s, const float* __restrict__ part_q,
                              const float* __restrict__ g, const float* __restrict__ b,
                              float* __restrict__ scale, float* __restrict__ shift) {
  int c = blockIdx.x * 256 + threadIdx.x;
  if (c >= IND) return;
  float s = 0.f, q = 0.f;
  for (int z = 0; z < 64; ++z) {
    s += part_s[(size_t)z * KP1 + c];
    q += part_q[(size_t)z * KP1 + c];
  }
  const float invN = 1.f / (float)B_;
  float mean = s * invN;
  float var = q * invN - mean * mean;
  float sc = g[c] * rsqrtf(var + BNEPS);
  scale[c] = sc;
  shift[c] = b[c] - mean * sc;
}

// ---------------- W' = bf16(enc_W * scale0), bias1 = enc_b + shift0 . enc_W^T ----------------
__global__ void prepw_k(const float* __restrict__ encW, const float* __restrict__ enc_b,
                        const float* __restrict__ scale0, const float* __restrict__ shift0,
                        bf16* __restrict__ Wp, float* __restrict__ bias1) {
  const int e = blockIdx.x;  // 512
  float local = 0.f;
  for (int j0 = threadIdx.x * 4; j0 < KP1; j0 += 1024) {
    ushort4 o;
    if (j0 < IND) {
      f32x4 w = *(const f32x4*)(encW + (size_t)e * IND + j0);
      f32x4 sc = *(const f32x4*)(scale0 + j0);
      f32x4 sh = *(const f32x4*)(shift0 + j0);
      local += sh[0] * w[0] + sh[1] * w[1] + sh[2] * w[2] + sh[3] * w[3];
      o.x = f2bfu(w[0] * sc[0]); o.y = f2bfu(w[1] * sc[1]);
      o.z = f2bfu(w[2] * sc[2]); o.w = f2bfu(w[3] * sc[3]);
    } else {
      o.x = 0; o.y = 0; o.z = 0; o.w = 0;
    }
    *(ushort4*)((u16*)Wp + (size_t)e * KP1 + j0) = o;
  }
#pragma unroll
  for (int o = 32; o > 0; o >>= 1) local += __shfl_down(local, o, 64);
  __shared__ float red[4];
  if ((threadIdx.x & 63) == 0) red[threadIdx.x >> 6] = local;
  __syncthreads();
  if (threadIdx.x == 0) bias1[e] = enc_b[e] + ((red[0] + red[1]) + (red[2] + red[3]));
}

// ---------------- GEMM1: 256x256 8-wave 8-phase counted-vmcnt, split-K=16 ----------------
__global__ __launch_bounds__(512, 2)
void gemm1_k(const bf16* __restrict__ A, const bf16* __restrict__ Bm,
             float* __restrict__ Cp) {
  extern __shared__ __align__(16) bf16 smem[];  // 128 KiB
  bf16* Asm = smem;
  bf16* Bsm = smem + 32768;
  const int tid = threadIdx.x;
  const int lane = tid & 63;
  const int wave = tid >> 6;
  const int wr = wave >> 2;
  const int wc = wave & 3;

  // chunked XCD swizzle, nwg = 256
  const int bid = blockIdx.x;
  const int swz = (bid & 7) * 32 + (bid >> 3);
  const int xm = swz & 7;
  const int rest = swz >> 3;
  const int yn = rest & 1;
  const int z = rest >> 1;
  const int m0 = xm * 256;
  const int n0 = yn * 256;
  const int kbeg = z * KSTEP1 * 64;

  const int srow = tid >> 3;
  const int schunk = (tid & 7) ^ (srow & 7);
  const bf16* gA = A + (size_t)(m0 + srow) * KP1 + kbeg + schunk * 8;
  const bf16* gB = Bm + (size_t)(n0 + srow) * KP1 + kbeg + schunk * 8;
  const int dst1 = tid * 8;

  const int lrow = lane & 15;
  const int kq = lane >> 4;
  const int rsw = lrow & 7;

  f32x4 acc[8][4] = {};
  bf16x8 bfv[4][2];

  auto SA = [&](int kt, int half) {
    const bf16* g = gA + (size_t)(half * 128) * KP1 + (size_t)kt * 64;
    bf16* l = Asm + (((kt & 1) * 2 + half) << 13) + dst1;
    gload_lds16(g, l);
    gload_lds16(g + (size_t)64 * KP1, l + 4096);
  };
  auto SB = [&](int kt, int half) {
    const bf16* g = gB + (size_t)(half * 128) * KP1 + (size_t)kt * 64;
    bf16* l = Bsm + (((kt & 1) * 2 + half) << 13) + dst1;
    gload_lds16(g, l);
    gload_lds16(g + (size_t)64 * KP1, l + 4096);
  };
  auto DSA = [&](int slot, int p, bf16x8 af[2][2]) {
#pragma unroll
    for (int i = 0; i < 2; ++i) {
      const int m = 2 * p + i;
      const int base = ((slot * 2 + (m >> 2)) * 128 + (m & 3) * 32 + wr * 16 + lrow) * 64;
#pragma unroll
      for (int kk = 0; kk < 2; ++kk)
        af[i][kk] = *(const bf16x8*)(&Asm[base + (((kk * 4 + kq) ^ rsw) << 3)]);
    }
  };
  auto DSB = [&](int slot) {
#pragma unroll
    for (int n = 0; n < 4; ++n) {
      const int base = ((slot * 2 + (wc >> 1)) * 128 + (wc & 1) * 64 + n * 16 + lrow) * 64;
#pragma unroll
      for (int kk = 0; kk < 2; ++kk)
        bfv[n][kk] = *(const bf16x8*)(&Bsm[base + (((kk * 4 + kq) ^ rsw) << 3)]);
    }
  };
  auto MF = [&](int p, bf16x8 af[2][2]) {
    __builtin_amdgcn_s_setprio(1);
#pragma unroll
    for (int i = 0; i < 2; ++i)
#pragma unroll
      for (int n = 0; n < 4; ++n)
#pragma unroll
        for (int kk = 0; kk < 2; ++kk)
          acc[2 * p + i][n] = __builtin_amdgcn_mfma_f32_16x16x32_bf16(
              bfv[n][kk], af[i][kk], acc[2 * p + i][n], 0, 0, 0);
    __builtin_amdgcn_s_setprio(0);
  };

  SA(0, 0); SA(0, 1); SB(0, 0); SB(0, 1);
  SB(1, 0); SB(1, 1); SA(1, 0);
  asm volatile("s_waitcnt vmcnt(6)" ::: "memory");
  __builtin_amdgcn_s_barrier();

  const int iters = KSTEP1 >> 1;
  for (int t = 0; t < iters; ++t) {
    const int e = 2 * t;
    const bool last = (t == iters - 1);
    bf16x8 af[2][2];
    DSB(0); DSA(0, 0, af);
    SA(e + 1, 1);
    __builtin_amdgcn_s_barrier();
    MF(0, af);
    __builtin_amdgcn_s_barrier();
    DSA(0, 1, af);
    if (!last) SB(e + 2, 0);
    __builtin_amdgcn_s_barrier();
    MF(1, af);
    __builtin_amdgcn_s_barrier();
    DSA(0, 2, af);
    if (!last) SB(e + 2, 1);
    __builtin_amdgcn_s_barrier();
    MF(2, af);
    __builtin_amdgcn_s_barrier();
    DSA(0, 3, af);
    if (!last) SA(e + 2, 0);
    if (last) { asm volatile("s_waitcnt vmcnt(0)" ::: "memory"); }
    else      { asm volatile("s_waitcnt vmcnt(6)" ::: "memory"); }
    __builtin_amdgcn_s_barrier();
    MF(3, af);
    __builtin_amdgcn_s_barrier();
    DSB(1); DSA(1, 0, af);
    if (!last) SA(e + 2, 1);
    __builtin_amdgcn_s_barrier();
    MF(0, af);
    __builtin_amdgcn_s_barrier();
    DSA(1, 1, af);
    if (!last) SB(e + 3, 0);
    __builtin_amdgcn_s_barrier();
    MF(1, af);
    __builtin_amdgcn_s_barrier();
    DSA(1, 2, af);
    if (!last) SB(e + 3, 1);
    __builtin_amdgcn_s_barrier();
    MF(2, af);
    __builtin_amdgcn_s_barrier();
    DSA(1, 3, af);
    if (!last) SA(e + 3, 0);
    if (last) { asm volatile("s_waitcnt vmcnt(0)" ::: "memory"); }
    else      { asm volatile("s_waitcnt vmcnt(6)" ::: "memory"); }
    __builtin_amdgcn_s_barrier();
    MF(3, af);
    __builtin_amdgcn_s_barrier();
  }

  float* o0 = Cp + (size_t)z * ((size_t)B_ * ENCN);
  const int gcolb = n0 + wc * 64 + kq * 4;
#pragma unroll
  for (int m = 0; m < 8; ++m) {
    const int grow = m0 + m * 32 + wr * 16 + lrow;
#pragma unroll
    for (int n = 0; n < 4; ++n) {
      const int gcol = gcolb + n * 16;
      *(f32x4*)(&o0[(size_t)grow * ENCN + gcol]) = acc[m][n];
    }
  }
}

// ---------------- combined output GEMMs: one launch, g in {0:pai,1:M,2:theta} ----------------
__global__ __launch_bounds__(512, 2)
void gemm_out_k(const bf16* __restrict__ A, const bf16* __restrict__ Wall,
                const float* __restrict__ b0, const float* __restrict__ b1,
                const float* __restrict__ b2,
                const float* __restrict__ sArr, float* __restrict__ out) {
  extern __shared__ __align__(16) bf16 smem[];  // 128 KiB
  bf16* Asm = smem;
  bf16* Bsm = smem + 32768;
  const int tid = threadIdx.x;
  const int lane = tid & 63;
  const int wave = tid >> 6;
  const int wr = wave >> 2;
  const int wc = wave & 3;

  // chunked XCD swizzle over nwg = 1896 (= 8*237); g = which GEMM
  const int bid = blockIdx.x;
  const int swz = (bid & 7) * 237 + (bid >> 3);
  const int g = swz / 632;
  const int r2 = swz - g * 632;
  const int xm = r2 & 7;
  const int yn = r2 >> 3;               // 0..78
  const int m0 = xm * 256;
  const int n0 = yn * 256;

  const bf16* Bm = Wall + (size_t)g * ((size_t)NP * ENCN);
  const float* bg = (g == 0) ? b0 : (g == 1) ? b1 : b2;
  const size_t OFF = (size_t)B_ * IND;
  float* o0 = out + (size_t)g * OFF;
  float* o1 = out + 3 * OFF;

  const int srow = tid >> 3;
  const int schunk = (tid & 7) ^ (srow & 7);
  const bf16* gA = A + (size_t)(m0 + srow) * ENCN + schunk * 8;
  const bf16* gB = Bm + (size_t)(n0 + srow) * ENCN + schunk * 8;
  const int dst1 = tid * 8;

  const int lrow = lane & 15;
  const int kq = lane >> 4;
  const int rsw = lrow & 7;

  f32x4 acc[8][4] = {};
  bf16x8 bfv[4][2];

  auto SA = [&](int kt, int half) {
    const bf16* g_ = gA + (size_t)(half * 128) * ENCN + (size_t)kt * 64;
    bf16* l = Asm + (((kt & 1) * 2 + half) << 13) + dst1;
    gload_lds16(g_, l);
    gload_lds16(g_ + (size_t)64 * ENCN, l + 4096);
  };
  auto SB = [&](int kt, int half) {
    const bf16* g_ = gB + (size_t)(half * 128) * ENCN + (size_t)kt * 64;
    bf16* l = Bsm + (((kt & 1) * 2 + half) << 13) + dst1;
    gload_lds16(g_, l);
    gload_lds16(g_ + (size_t)64 * ENCN, l + 4096);
  };
  auto DSA = [&](int slot, int p, bf16x8 af[2][2]) {
#pragma unroll
    for (int i = 0; i < 2; ++i) {
      const int m = 2 * p + i;
      const int base = ((slot * 2 + (m >> 2)) * 128 + (m & 3) * 32 + wr * 16 + lrow) * 64;
#pragma unroll
      for (int kk = 0; kk < 2; ++kk)
        af[i][kk] = *(const bf16x8*)(&Asm[base + (((kk * 4 + kq) ^ rsw) << 3)]);
    }
  };
  auto DSB = [&](int slot) {
#pragma unroll
    for (int n = 0; n < 4; ++n) {
      const int base = ((slot * 2 + (wc >> 1)) * 128 + (wc & 1) * 64 + n * 16 + lrow) * 64;
#pragma unroll
      for (int kk = 0; kk < 2; ++kk)
        bfv[n][kk] = *(const bf16x8*)(&Bsm[base + (((kk * 4 + kq) ^ rsw) << 3)]);
    }
  };
  auto MF = [&](int p, bf16x8 af[2][2]) {
    __builtin_amdgcn_s_setprio(1);
#pragma unroll
    for (int i = 0; i < 2; ++i)
#pragma unroll
      for (int n = 0; n < 4; ++n)
#pragma unroll
        for (int kk = 0; kk < 2; ++kk)
          acc[2 * p + i][n] = __builtin_amdgcn_mfma_f32_16x16x32_bf16(
              bfv[n][kk], af[i][kk], acc[2 * p + i][n], 0, 0, 0);
    __builtin_amdgcn_s_setprio(0);
  };

  SA(0, 0); SA(0, 1); SB(0, 0); SB(0, 1);
  SB(1, 0); SB(1, 1); SA(1, 0);
  asm volatile("s_waitcnt vmcnt(6)" ::: "memory");
  __builtin_amdgcn_s_barrier();

  const int iters = 4;  // ksteps = 8 (K=512)
  for (int t = 0; t < iters; ++t) {
    const int e = 2 * t;
    const bool last = (t == iters - 1);
    bf16x8 af[2][2];
    DSB(0); DSA(0, 0, af);
    SA(e + 1, 1);
    __builtin_amdgcn_s_barrier();
    MF(0, af);
    __builtin_amdgcn_s_barrier();
    DSA(0, 1, af);
    if (!last) SB(e + 2, 0);
    __builtin_amdgcn_s_barrier();
    MF(1, af);
    __builtin_amdgcn_s_barrier();
    DSA(0, 2, af);
    if (!last) SB(e + 2, 1);
    __builtin_amdgcn_s_barrier();
    MF(2, af);
    __builtin_amdgcn_s_barrier();
    DSA(0, 3, af);
    if (!last) SA(e + 2, 0);
    if (last) { asm volatile("s_waitcnt vmcnt(0)" ::: "memory"); }
    else      { asm volatile("s_waitcnt vmcnt(6)" ::: "memory"); }
    __builtin_amdgcn_s_barrier();
    MF(3, af);
    __builtin_amdgcn_s_barrier();
    DSB(1); DSA(1, 0, af);
    if (!last) SA(e + 2, 1);
    __builtin_amdgcn_s_barrier();
    MF(0, af);
    __builtin_amdgcn_s_barrier();
    DSA(1, 1, af);
    if (!last) SB(e + 3, 0);
    __builtin_amdgcn_s_barrier();
    MF(1, af);
    __builtin_amdgcn_s_barrier();
    DSA(1, 2, af);
    if (!last) SB(e + 3, 1);
    __builtin_amdgcn_s_barrier();
    MF(2, af);
    __builtin_amdgcn_s_barrier();
    DSA(1, 3, af);
    if (!last) SA(e + 3, 0);
    if (last) { asm volatile("s_waitcnt vmcnt(0)" ::: "memory"); }
    else      { asm volatile("s_waitcnt vmcnt(6)" ::: "memory"); }
    __builtin_amdgcn_s_barrier();
    MF(3, af);
    __builtin_amdgcn_s_barrier();
  }

  const int gcolb = n0 + wc * 64 + kq * 4;
#pragma unroll
  for (int m = 0; m < 8; ++m) {
    const int grow = m0 + m * 32 + wr * 16 + lrow;
    float srow_s = 0.f;
    if (g == 1) srow_s = sArr[grow];
#pragma unroll
    for (int n = 0; n < 4; ++n) {
      const int gcol = gcolb + n * 16;
      if (gcol < IND) {
        f32x4 bb = *(const f32x4*)(&bg[gcol]);
        f32x4 t = acc[m][n] + bb;
        f32x4 r;
        if (g == 0) {
#pragma unroll
          for (int j = 0; j < 4; ++j) r[j] = 1.f / (1.f + __expf(-t[j]));
          *(f32x4*)(&o0[(size_t)grow * IND + gcol]) = r;
        } else {
#pragma unroll
          for (int j = 0; j < 4; ++j) r[j] = __expf(t[j]);
          *(f32x4*)(&o0[(size_t)grow * IND + gcol]) = r;
          if (g == 1) {
            f32x4 rl;
#pragma unroll
            for (int j = 0; j < 4; ++j) rl[j] = srow_s * r[j];
            *(f32x4*)(&o1[(size_t)grow * IND + gcol]) = rl;
          }
        }
      }
    }
  }
}

// ---------------- mid GEMMs (128x128, 4-wave, f32 inputs staged w/ affine) ----------------
// EPI 0: raw f32x4 partial store (GEMM2 split-K); EPI 1: bias+relu -> bf16 (GEMM3)
template <int EPI>
__global__ __launch_bounds__(256, 2)
void gemm_mid_k(const float* __restrict__ A, int lda,
                const float* __restrict__ scl, const float* __restrict__ sft,
                const float* __restrict__ W, int ldb,
                const float* __restrict__ bias,
                float* __restrict__ outP, bf16* __restrict__ outB, int ldo) {
  __shared__ __align__(16) bf16 As[128 * 64];
  __shared__ __align__(16) bf16 Bs[128 * 64];
  const int tid = threadIdx.x;
  const int lane = tid & 63;
  const int wave = tid >> 6;
  const int wr = wave >> 1, wc = wave & 1;
  const int m0 = blockIdx.x * 128;
  const int n0 = blockIdx.y * 128;
  const int z = blockIdx.z;
  const int kbeg = z * 128;
  const int lrow = lane & 15;
  const int kq = lane >> 4;
  const int scol = lrow * 4;
  const int srow0 = wave * 32 + kq;

  f32x4 acc[4][4] = {};
  for (int ks = 0; ks < 2; ++ks) {
    const int kb = kbeg + ks * 64;
    f32x4 sc4 = *(const f32x4*)(scl + kb + scol);
    f32x4 sf4 = *(const f32x4*)(sft + kb + scol);
#pragma unroll
    for (int i = 0; i < 8; ++i) {
      const int r = srow0 + i * 4;
      const int byte = r * 128 + (((lrow >> 1) ^ (r & 7)) << 4) + ((lrow & 1) << 3);
      f32x4 a = *(const f32x4*)(A + (size_t)(m0 + r) * lda + kb + scol);
      a = a * sc4 + sf4;
      st_b64_bf16((char*)As + byte, a);
      f32x4 b = *(const f32x4*)(W + (size_t)(n0 + r) * ldb + kb + scol);
      st_b64_bf16((char*)Bs + byte, b);
    }
    __syncthreads();
#pragma unroll
    for (int kk = 0; kk < 2; ++kk) {
      const int kc = kk * 4 + kq;
      bf16x8 af[4], bfv[4];
#pragma unroll
      for (int m = 0; m < 4; ++m) {
        const int row = wr * 64 + m * 16 + lrow;
        af[m] = *(const bf16x8*)(&As[row * 64 + (((kc ^ (row & 7)) & 7) << 3)]);
      }
#pragma unroll
      for (int n = 0; n < 4; ++n) {
        const int row = wc * 64 + n * 16 + lrow;
        bfv[n] = *(const bf16x8*)(&Bs[row * 64 + (((kc ^ (row & 7)) & 7) << 3)]);
      }
#pragma unroll
      for (int m = 0; m < 4; ++m)
#pragma unroll
        for (int n = 0; n < 4; ++n)
          acc[m][n] = __builtin_amdgcn_mfma_f32_16x16x32_bf16(bfv[n], af[m], acc[m][n], 0, 0, 0);
    }
    __syncthreads();
  }

  const int growb = m0 + wr * 64 + lrow;
  const int gcolb = n0 + wc * 64 + kq * 4;
#pragma unroll
  for (int m = 0; m < 4; ++m) {
    const int grow = growb + m * 16;
#pragma unroll
    for (int n = 0; n < 4; ++n) {
      const int gcol = gcolb + n * 16;
      if (EPI == 0) {
        float* op = outP + (size_t)z * ((size_t)B_ * ldo);
        *(f32x4*)(&op[(size_t)grow * ldo + gcol]) = acc[m][n];
      } else {
        f32x4 t = acc[m][n] + *(const f32x4*)(&bias[gcol]);
        f32x4 r;
#pragma unroll
        for (int j = 0; j < 4; ++j) r[j] = fmaxf(t[j], 0.f);
        st_b64_bf16((u16*)outB + (size_t)grow * ldo + gcol, r);
      }
    }
  }
}

// ---------------- split-K reduce + bias + relu + BN1 col-partials ----------------
__global__ void reduce1c_k(const float* __restrict__ Cp, const float* __restrict__ bias1,
                           float* __restrict__ C1, float* __restrict__ ps,
                           float* __restrict__ pq) {
  const int b = blockIdx.x;          // 256 blocks, 8 rows each
  const int t = threadIdx.x;         // 256
  const int c4 = (t & 127) * 4;
  const int rs = t >> 7;
  f32x4 bb = *(const f32x4*)(bias1 + c4);
  f32x4 sum = {0.f, 0.f, 0.f, 0.f}, sq = {0.f, 0.f, 0.f, 0.f};
#pragma unroll
  for (int rr = 0; rr < 4; ++rr) {
    const int row = b * 8 + rs + rr * 2;
    f32x4 v = {0.f, 0.f, 0.f, 0.f};
#pragma unroll
    for (int z = 0; z < SPLITK; ++z)
      v += *(const f32x4*)(Cp + (size_t)z * (B_ * ENCN) + (size_t)row * ENCN + c4);
    v += bb;
    f32x4 r;
#pragma unroll
    for (int j = 0; j < 4; ++j) r[j] = fmaxf(v[j], 0.f);
    *(f32x4*)(C1 + (size_t)row * ENCN + c4) = r;
    sum += r; sq += r * r;
  }
  __shared__ f32x4 ls[2][128], lq[2][128];
  ls[rs][t & 127] = sum; lq[rs][t & 127] = sq;
  __syncthreads();
  if (t < 128) {
    f32x4 s = ls[0][t] + ls[1][t];
    f32x4 q = lq[0][t] + lq[1][t];
    *(f32x4*)(ps + (size_t)b * ENCN + t * 4) = s;
    *(f32x4*)(pq + (size_t)b * ENCN + t * 4) = q;
  }
}

// ---------------- split-K reduce + bias + relu + BN2 col-partials (GEMM2) ----------------
__global__ void reduce2c_k(const float* __restrict__ Cp2, const float* __restrict__ bias,
                           float* __restrict__ C2, float* __restrict__ ps,
                           float* __restrict__ pq) {
  const int b = blockIdx.x;      // 128 blocks, 16 rows each
  const int t = threadIdx.x;     // 256
  const int c4 = (t & 31) * 4;
  const int rs = t >> 5;         // 0..7
  f32x4 bb = *(const f32x4*)(bias + c4);
  f32x4 sum = {0.f, 0.f, 0.f, 0.f}, sq = {0.f, 0.f, 0.f, 0.f};
#pragma unroll
  for (int rr = 0; rr < 2; ++rr) {
    const int row = b * 16 + rs + rr * 8;
    f32x4 v = {0.f, 0.f, 0.f, 0.f};
#pragma unroll
    for (int z = 0; z < SPLITK2; ++z)
      v += *(const f32x4*)(Cp2 + (size_t)z * (B_ * BOTN) + (size_t)row * BOTN + c4);
    v += bb;
    f32x4 r;
#pragma unroll
    for (int j = 0; j < 4; ++j) r[j] = fmaxf(v[j], 0.f);
    *(f32x4*)(C2 + (size_t)row * BOTN + c4) = r;
    sum += r; sq += r * r;
  }
  __shared__ f32x4 ls[8][32], lq[8][32];
  ls[rs][t & 31] = sum; lq[rs][t & 31] = sq;
  __syncthreads();
  if (t < 32) {
    f32x4 s = {0.f, 0.f, 0.f, 0.f}, q = {0.f, 0.f, 0.f, 0.f};
#pragma unroll
    for (int k = 0; k < 8; ++k) { s += ls[k][t]; q += lq[k][t]; }
    *(f32x4*)(ps + (size_t)b * BOTN + t * 4) = s;
    *(f32x4*)(pq + (size_t)b * BOTN + t * 4) = q;
  }
}

// ---------------- finalize BN1/BN2 scale+shift from partials ----------------
__global__ void colfin_k(const float* __restrict__ ps, const float* __restrict__ pq,
                         const float* __restrict__ g, const float* __restrict__ b,
                         float* __restrict__ scale, float* __restrict__ shift,
                         int C, int nPart) {
  const int cl = threadIdx.x & 63;
  const int pg = threadIdx.x >> 6;   // 0..3
  const int c = blockIdx.x * 64 + cl;
  float s = 0.f, q = 0.f;
  for (int p = pg; p < nPart; p += 4) {
    s += ps[(size_t)p * C + c];
    q += pq[(size_t)p * C + c];
  }
  __shared__ float ls[4][64], lq[4][64];
  ls[pg][cl] = s; lq[pg][cl] = q;
  __syncthreads();
  if (pg == 0) {
    s = (ls[0][cl] + ls[1][cl]) + (ls[2][cl] + ls[3][cl]);
    q = (lq[0][cl] + lq[1][cl]) + (lq[2][cl] + lq[3][cl]);
    const float invN = 1.f / (float)B_;
    float mean = s * invN;
    float var = q * invN - mean * mean;
    float sc = g[c] * rsqrtf(var + BNEPS);
    scale[c] = sc;
    shift[c] = b[c] - mean * sc;
  }
}

// ---------------- all 3 output weights -> bf16 (3 segments, padded rows = 0) ----------------
__global__ void cvt_all_k(const float* __restrict__ W0, const float* __restrict__ W1,
                          const float* __restrict__ W2, bf16* __restrict__ Wb) {
  const size_t SEG = (size_t)NP * 512;
  const size_t idx = ((size_t)blockIdx.x * 256 + threadIdx.x) * 4;  // < 3*SEG
  const int seg = (int)(idx / SEG);
  const size_t rem = idx - (size_t)seg * SEG;
  const int e = (int)(rem >> 9);
  const float* src = (seg == 0) ? W0 : (seg == 1) ? W1 : W2;
  ushort4 o;
  if (e < IND) {
    f32x4 v = *(const f32x4*)(src + rem);
    o.x = f2bfu(v[0]); o.y = f2bfu(v[1]); o.z = f2bfu(v[2]); o.w = f2bfu(v[3]);
  } else {
    o.x = 0; o.y = 0; o.z = 0; o.w = 0;
  }
  *(ushort4*)((u16*)Wb + idx) = o;
}

extern "C" void kernel_launch(void* const* d_in, const int* in_sizes, int n_in,
                              void* d_out, int out_size, void* d_ws, size_t ws_size,
                              hipStream_t stream) {
  const float* x     = (const float*)d_in[0];
  const float* bn0_g = (const float*)d_in[1];
  const float* bn0_b = (const float*)d_in[2];
  const float* enc_W = (const float*)d_in[3];
  const float* enc_b = (const float*)d_in[4];
  const float* bn1_g = (const float*)d_in[5];
  const float* bn1_b = (const float*)d_in[6];
  const float* bot_W = (const float*)d_in[7];
  const float* bot_b = (const float*)d_in[8];
  const float* bn2_g = (const float*)d_in[9];
  const float* bn2_b = (const float*)d_in[10];
  const float* dec_W = (const float*)d_in[11];
  const float* dec_b = (const float*)d_in[12];
  const float* o1_W  = (const float*)d_in[13];
  const float* o1_b  = (const float*)d_in[14];
  const float* o2_W  = (const float*)d_in[15];
  const float* o2_b  = (const float*)d_in[16];
  const float* o3_W  = (const float*)d_in[17];
  const float* o3_b  = (const float*)d_in[18];

  char* wsb = (char*)d_ws;
  size_t off = 0;
  auto alloc = [&](size_t bytes) -> void* {
    void* p = wsb + off;
    off = (off + bytes + 255) & ~(size_t)255;
    return p;
  };
  float* row_sum = (float*)alloc(B_ * 4);
  float* sArr    = (float*)alloc(B_ * 4);
  float* invs    = (float*)alloc(B_ * 4);
  float* scale0  = (float*)alloc(IND * 4);
  float* shift0  = (float*)alloc(IND * 4);
  float* bias1   = (float*)alloc(ENCN * 4);
  float* scale1  = (float*)alloc(ENCN * 4);
  float* shift1  = (float*)alloc(ENCN * 4);
  float* scale2  = (float*)alloc(BOTN * 4);
  float* shift2  = (float*)alloc(BOTN * 4);
  float* ps1     = (float*)alloc(256 * ENCN * 4);
  float* pq1     = (float*)alloc(256 * ENCN * 4);
  float* ps2     = (float*)alloc(128 * BOTN * 4);
  float* pq2     = (float*)alloc(128 * BOTN * 4);
  float* C1      = (float*)alloc((size_t)B_ * ENCN * 4);
  float* C2f     = (float*)alloc((size_t)B_ * BOTN * 4);
  float* Cp2     = (float*)alloc((size_t)SPLITK2 * B_ * BOTN * 4);
  float* Cp      = (float*)alloc((size_t)SPLITK * B_ * ENCN * 4);
  bf16*  L       = (bf16*)alloc((size_t)B_ * KP1 * 2);
  bf16*  Wp      = (bf16*)alloc((size_t)ENCN * KP1 * 2);
  bf16*  h3      = (bf16*)alloc((size_t)B_ * DECN * 2);
  bf16*  Wall    = (bf16*)alloc((size_t)3 * NP * 512 * 2);
  // BN0 partials alias Cp (dead before GEMM1 writes Cp)
  float* part_s  = Cp;
  float* part_q  = Cp + (size_t)64 * KP1;

  hipFuncSetAttribute(reinterpret_cast<const void*>(gemm1_k),
                      hipFuncAttributeMaxDynamicSharedMemorySize, 131072);
  hipFuncSetAttribute(reinterpret_cast<const void*>(gemm_out_k),
                      hipFuncAttributeMaxDynamicSharedMemorySize, 131072);

  // 1. row sums + median scales
  rowsum_k<<<B_, 256, 0, stream>>>(x, row_sum);
  median_scale_k<<<1, 1024, 0, stream>>>(row_sum, sArr, invs);

  // 2. L = bf16(log1p(x/s)), BN0 stats
  pass2_k<<<dim3(KP1 / 1024, 64), 256, 0, stream>>>(x, invs, L, part_s, part_q);
  finalize_bn_k<<<(IND + 255) / 256, 256, 0, stream>>>(part_s, part_q, bn0_g, bn0_b,
                                                       scale0, shift0);

  // 3. fold BN0 into encoder weights
  prepw_k<<<ENCN, 256, 0, stream>>>(enc_W, enc_b, scale0, shift0, Wp, bias1);

  // 4. GEMM1 (256^2 8-phase, split-K=16) + fused reduce(+bias+relu+BN1 partials)
  gemm1_k<<<256, 512, 131072, stream>>>(L, Wp, Cp);
  reduce1c_k<<<256, 256, 0, stream>>>(Cp, bias1, C1, ps1, pq1);
  colfin_k<<<ENCN / 64, 256, 0, stream>>>(ps1, pq1, bn1_g, bn1_b, scale1, shift1,
                                          ENCN, 256);

  // 5. GEMM2 (affine-fused staging, split-K=4) -> reduce+BN2 partials -> GEMM3 -> h3
  gemm_mid_k<0><<<dim3(16, 1, SPLITK2), 256, 0, stream>>>(
      C1, ENCN, scale1, shift1, bot_W, ENCN, nullptr, Cp2, nullptr, BOTN);
  reduce2c_k<<<128, 256, 0, stream>>>(Cp2, bot_b, C2f, ps2, pq2);
  colfin_k<<<BOTN / 64, 256, 0, stream>>>(ps2, pq2, bn2_g, bn2_b, scale2, shift2,
                                          BOTN, 128);
  gemm_mid_k<1><<<dim3(16, 4, 1), 256, 0, stream>>>(
      C2f, BOTN, scale2, shift2, dec_W, BOTN, dec_b, nullptr, h3, DECN);

  // 6. all output weights -> bf16 in one launch (segment order: o2, o1, o3)
  cvt_all_k<<<(3 * NP * 512) / 1024, 256, 0, stream>>>(o2_W, o1_W, o3_W, Wall);

  // 7. combined output GEMMs (one launch, 1896 blocks) with fused epilogues
  float* out = (float*)d_out;
  gemm_out_k<<<1896, 512, 131072, stream>>>(h3, Wall, o2_b, o1_b, o3_b, sArr, out);
}